// Round 10
// baseline (429.286 us; speedup 1.0000x reference)
//
#include <hip/hip_runtime.h>

// VariationalMPS R12: R11 skeleton (multi-launch, paired sites, 512-thr blocks)
// with LDS-port-traffic-halved inner loops. Diagnosis: phases are LDS-read
// throughput bound (~36 port-cyc per 16 FMAs in R11). Fix:
//  eA: acc[8][4] per thread (32 FMAs/aa from 2xb128 L + 1xb128 M2 via [aa][p][I]
//      relayout); z splits the a-contraction, one-time LDS reduce.
//  eB: 4x8 microtile (32 FMAs/k from 1xb128 A-rows + 2xb128 B-cols), 8-way
//      wave-aligned k-split, As stride 36 (aligned 4-row b128), LDS reduce.
// prep1/prep2/norm paths/dot/loss verbatim R11.

#define D 128
#define W 8
#define NS 40
#define NPAIR 20
#define HALF2 10
#define MSZ (D * 2 * D)        // 32768
#define HSZ (W * W * 2 * 2)    // 256
#define M2SZ (D * 4 * D)       // 65536  [a][I][c] = a*512+I*128+c
#define H2SZ (W * W * 4 * 4)   // 1024   [w][x][I][J]
#define LSZ (D * W * D)        // 131072 [a][w][b] (= [p][x][q] after B)
#define NSZ (D * D)            // 16384
#define T2SZ (D * W * D * 4)   // 524288 [p][x][b][J] = row(p,x)*512 + b*4+J
#define TNSZ (4 * D * D)       // 65536  [I][p][b]

#define OFF_M2 0
#define OFF_MR2 (OFF_M2 + NPAIR * M2SZ)
#define OFF_H2 (OFF_MR2 + HALF2 * M2SZ)
#define OFF_HR2 (OFF_H2 + NPAIR * H2SZ)
#define OFF_LL (OFF_HR2 + HALF2 * H2SZ)
#define OFF_LR (OFF_LL + LSZ)
#define OFF_NL (OFF_LR + LSZ)
#define OFF_NR (OFF_NL + NSZ)
#define OFF_T2L (OFF_NR + NSZ)
#define OFF_T2R (OFF_T2L + T2SZ)
#define OFF_TNL (OFF_T2R + T2SZ)
#define OFF_TNR (OFF_TNL + TNSZ)
#define OFF_PART (OFF_TNR + TNSZ)
#define OFF_PARTN (OFF_PART + 128)

// ---------------- prep1: pair GEMMs M2 (640 blocks) + H2 (block 640) --------
__global__ __launch_bounds__(256) void k_prep1(const float* __restrict__ Min,
                                               const float* __restrict__ Hin,
                                               float* __restrict__ ws) {
    __shared__ float As[32 * 34];
    __shared__ float Bs[32 * 68];
    int bid = blockIdx.x, t = threadIdx.x;
    if (bid < 640) {
        int m = bid >> 5, tile = bid & 31;
        int r0 = (tile & 7) * 32, c0 = (tile >> 3) * 64;
        const float* A = Min + (2 * m) * MSZ;
        const float* B = Min + (2 * m + 1) * MSZ;
        float* C = ws + OFF_M2 + m * M2SZ;
        int ty = t >> 4, tx = t & 15;
        float a00 = 0, a01 = 0, a02 = 0, a03 = 0;
        float a10 = 0, a11 = 0, a12 = 0, a13 = 0;
        for (int c = 0; c < 4; ++c) {
            int k0 = c * 32;
            __syncthreads();
            {
                int rr = t >> 3, kq = t & 7;
                int row = r0 + rr;
                const float4 v = *(const float4*)&A[(row >> 1) * 256 + (row & 1) * 128 + k0 + kq * 4];
                float* dst = &As[kq * 136 + rr];
                dst[0] = v.x; dst[34] = v.y; dst[68] = v.z; dst[102] = v.w;
            }
#pragma unroll
            for (int u = 0; u < 2; ++u) {
                int e = u * 256 + t;
                int kk = e >> 4, cq = e & 15;
                const float4 v = *(const float4*)&B[(k0 + kk) * 256 + c0 + cq * 4];
                *(float4*)&Bs[kk * 68 + cq * 4] = v;
            }
            __syncthreads();
#pragma unroll 8
            for (int kk = 0; kk < 32; ++kk) {
                float2 av = *(float2*)&As[kk * 34 + 2 * ty];
                float4 bv = *(float4*)&Bs[kk * 68 + 4 * tx];
                a00 += av.x * bv.x; a01 += av.x * bv.y; a02 += av.x * bv.z; a03 += av.x * bv.w;
                a10 += av.y * bv.x; a11 += av.y * bv.y; a12 += av.y * bv.z; a13 += av.y * bv.w;
            }
        }
        int r = r0 + 2 * ty, cc = c0 + 4 * tx;
        int a = r >> 1, i2 = cc >> 7, cd = cc & 127;
        float4 v0; v0.x = a00; v0.y = a01; v0.z = a02; v0.w = a03;
        float4 v1; v1.x = a10; v1.y = a11; v1.z = a12; v1.w = a13;
        *(float4*)&C[a * 512 + (0 * 2 + i2) * 128 + cd] = v0;
        *(float4*)&C[a * 512 + (1 * 2 + i2) * 128 + cd] = v1;
    } else {
        for (int idx = t; idx < NPAIR * H2SZ; idx += 256) {
            int m = idx >> 10, r = idx & 1023;
            int w = r >> 7, x = (r >> 4) & 7, I = (r >> 2) & 3, J = r & 3;
            int i1 = I >> 1, i2 = I & 1, j1 = J >> 1, j2 = J & 1;
            const float* Ha = Hin + (2 * m) * HSZ;
            const float* Hb = Hin + (2 * m + 1) * HSZ;
            float s = 0.f;
#pragma unroll
            for (int v = 0; v < 8; ++v)
                s += Ha[w * 32 + v * 4 + i1 * 2 + j1] * Hb[v * 32 + x * 4 + i2 * 2 + j2];
            ws[OFF_H2 + idx] = s;
        }
    }
}

// ---------------- prep2: rev transposes + env init --------------------------
#define PR_MR (HALF2 * M2SZ)
#define PR_HR (PR_MR + HALF2 * H2SZ)
#define PR_TOT (PR_HR + 2 * LSZ + 2 * NSZ)
__global__ __launch_bounds__(256) void k_prep2(float* __restrict__ ws) {
    for (int idx = blockIdx.x * 256 + threadIdx.x; idx < PR_TOT; idx += gridDim.x * 256) {
        if (idx < PR_MR) {
            int kr = idx >> 16, r = idx & 65535;
            int a = r >> 9, I = (r >> 7) & 3, p = r & 127;
            ws[OFF_MR2 + idx] = ws[OFF_M2 + (19 - kr) * M2SZ + p * 512 + I * 128 + a];
        } else if (idx < PR_HR) {
            int e = idx - PR_MR;
            int kr = e >> 10, r = e & 1023;
            int w = r >> 7, x = (r >> 4) & 7, lo = r & 15;
            ws[OFF_HR2 + e] = ws[OFF_H2 + (19 - kr) * H2SZ + x * 128 + w * 16 + lo];
        } else {
            int e = idx - PR_HR;
            int off; float v = 0.f;
            if (e < LSZ)            { off = OFF_LL + e; if (e == 0) v = 1.f; }
            else if (e < 2 * LSZ)   { int r = e - LSZ; off = OFF_LR + r; if (r == (W - 1) * D) v = 1.f; }
            else if (e < 2 * LSZ + NSZ) { int r = e - 2 * LSZ; off = OFF_NL + r; if (r == 0) v = 1.f; }
            else                    { int r = e - 2 * LSZ - NSZ; off = OFF_NR + r; if (r == 0) v = 1.f; }
            ws[off] = v;
        }
    }
}

// ---------------- phase A (512 threads) -------------------------------------
// Energy blocks 0..127: thread = (b_l,p_l) of a 16x16 tile, acc[8w][4I];
// z splits a (z=0: a 0..63, z=1: a 64..127), LDS reduce, z0 fuses h2 + stores.
// Norm blocks 128..159: z = independent task (R11 verbatim).
__global__ __launch_bounds__(512) void k_A2(float* __restrict__ ws, int k) {
    __shared__ __align__(16) float sm[17920];
    int bid = blockIdx.x, t = threadIdx.x;
    int z = t >> 8, tl = t & 255;
    if (bid < 128) {
        int side = bid >> 6;
        int eb = bid & 63;
        int b0 = (eb & 7) * 16;
        int p0 = (eb >> 3) * 16;
        const float* Lsrc = ws + (side ? OFF_LR : OFF_LL);
        const float* m2 = ws + (side ? OFF_MR2 : OFF_M2) + k * M2SZ;
        const float* h2 = ws + (side ? OFF_HR2 : OFF_H2) + k * H2SZ;
        float* T2 = ws + (side ? OFF_T2R : OFF_T2L);
        float* Ls = sm + z * 6400;        // [32a][16b][12w-pad] stride 200
        float* ms = sm + 12800 + z * 2048; // [32a][16p][4I]
        float* hs = sm + 16896;            // [32 wI][32 xJ]
#pragma unroll
        for (int u = 0; u < 2; ++u) {   // stage h2
            int e = u * 512 + t;
            int w = e >> 7, I = (e >> 5) & 3, x = (e >> 2) & 7, J = e & 3;
            hs[e] = h2[w * 128 + x * 16 + I * 4 + J];
        }
        int b_l = tl & 15, p_l = tl >> 4;
        float acc[8][4];
#pragma unroll
        for (int w = 0; w < 8; ++w)
#pragma unroll
            for (int I = 0; I < 4; ++I) acc[w][I] = 0.f;
        // per-element staging coords
        int la[4], lw[4], lb[4], maa[2], mI[2], mpq[2];
#pragma unroll
        for (int u = 0; u < 4; ++u) {
            int e = u * 256 + tl;
            la[u] = e >> 5; lw[u] = (e >> 2) & 7; lb[u] = e & 3;
        }
#pragma unroll
        for (int u = 0; u < 2; ++u) {
            int e = u * 256 + tl;
            maa[u] = e >> 4; mI[u] = (e >> 2) & 3; mpq[u] = e & 3;
        }
        // prefetch chunk 0 of this z (a0 = z*64)
        float4 pl[4], pm[2];
        {
            int a0 = z * 64;
#pragma unroll
            for (int u = 0; u < 4; ++u)
                pl[u] = *(const float4*)&Lsrc[(a0 + la[u]) * 1024 + lw[u] * 128 + b0 + lb[u] * 4];
#pragma unroll
            for (int u = 0; u < 2; ++u)
                pm[u] = *(const float4*)&m2[(a0 + maa[u]) * 512 + mI[u] * 128 + p0 + mpq[u] * 4];
        }
        for (int c = 0; c < 2; ++c) {
            __syncthreads();
#pragma unroll
            for (int u = 0; u < 4; ++u) {
                float* dst = &Ls[la[u] * 200 + lb[u] * 48 + lw[u]];
                dst[0] = pl[u].x; dst[12] = pl[u].y; dst[24] = pl[u].z; dst[36] = pl[u].w;
            }
#pragma unroll
            for (int u = 0; u < 2; ++u) {   // ms[aa][p][I]: scatter over p
                int base = maa[u] * 64 + mpq[u] * 16 + mI[u];
                ms[base] = pm[u].x; ms[base + 4] = pm[u].y;
                ms[base + 8] = pm[u].z; ms[base + 12] = pm[u].w;
            }
            if (c == 0) {
                int a0 = z * 64 + 32;
#pragma unroll
                for (int u = 0; u < 4; ++u)
                    pl[u] = *(const float4*)&Lsrc[(a0 + la[u]) * 1024 + lw[u] * 128 + b0 + lb[u] * 4];
#pragma unroll
                for (int u = 0; u < 2; ++u)
                    pm[u] = *(const float4*)&m2[(a0 + maa[u]) * 512 + mI[u] * 128 + p0 + mpq[u] * 4];
            }
            __syncthreads();
#pragma unroll 4
            for (int aa = 0; aa < 32; ++aa) {
                float4 l0 = *(float4*)&Ls[aa * 200 + b_l * 12];
                float4 l1 = *(float4*)&Ls[aa * 200 + b_l * 12 + 4];
                float4 mv = *(float4*)&ms[aa * 64 + p_l * 4];
                float lv[8] = {l0.x, l0.y, l0.z, l0.w, l1.x, l1.y, l1.z, l1.w};
#pragma unroll
                for (int w = 0; w < 8; ++w) {
                    acc[w][0] += lv[w] * mv.x;
                    acc[w][1] += lv[w] * mv.y;
                    acc[w][2] += lv[w] * mv.z;
                    acc[w][3] += lv[w] * mv.w;
                }
            }
        }
        // reduce z1 -> z0 (red aliases Ls region, dead after sync)
        __syncthreads();
        float* red = sm;
        if (z == 1) {
#pragma unroll
            for (int w = 0; w < 8; ++w) {
                float4 v; v.x = acc[w][0]; v.y = acc[w][1]; v.z = acc[w][2]; v.w = acc[w][3];
                *(float4*)&red[tl * 32 + w * 4] = v;
            }
        }
        __syncthreads();
        if (z == 0) {
#pragma unroll
            for (int w = 0; w < 8; ++w) {
                float4 v = *(float4*)&red[tl * 32 + w * 4];
                acc[w][0] += v.x; acc[w][1] += v.y; acc[w][2] += v.z; acc[w][3] += v.w;
            }
            float o[32];
#pragma unroll
            for (int xJ = 0; xJ < 32; ++xJ) o[xJ] = 0.f;
#pragma unroll
            for (int wI = 0; wI < 32; ++wI) {
                float tv = acc[wI >> 2][wI & 3];
#pragma unroll
                for (int xJ = 0; xJ < 32; ++xJ) o[xJ] += tv * hs[wI * 32 + xJ];
            }
            int b = b0 + b_l, p = p0 + p_l;
#pragma unroll
            for (int x = 0; x < 8; ++x) {
                float4 v; v.x = o[x * 4]; v.y = o[x * 4 + 1];
                v.z = o[x * 4 + 2]; v.w = o[x * 4 + 3];
                *(float4*)&T2[p * 4096 + x * 512 + b * 4] = v;
            }
        }
    } else {
        int g = (bid - 128) * 2 + z;     // 0..63 (R11 verbatim)
        int side = g >> 5;
        int nn = g & 31;
        int b0 = (nn & 3) * 32;
        int c0 = (nn >> 2) * 64;
        const float* Nsrc = ws + (side ? OFF_NR : OFF_NL);
        const float* m2 = ws + (side ? OFF_MR2 : OFF_M2) + k * M2SZ;
        float* Tn = ws + (side ? OFF_TNR : OFF_TNL);
        float* As = sm + z * 3264;
        float* Bs = sm + z * 3264 + 1056;
        int ty = tl >> 4, tx = tl & 15;
        float a00 = 0, a01 = 0, a02 = 0, a03 = 0;
        float a10 = 0, a11 = 0, a12 = 0, a13 = 0;
        for (int c = 0; c < 4; ++c) {
            int a0 = c * 32;
            __syncthreads();
#pragma unroll
            for (int u = 0; u < 4; ++u) {
                int e = u * 256 + tl;
                int kk = e >> 5, col = e & 31;
                As[kk * 33 + col] = Nsrc[(a0 + kk) * 128 + b0 + col];
            }
#pragma unroll
            for (int u = 0; u < 8; ++u) {
                int e = u * 256 + tl;
                int kk = e >> 6, col = e & 63;
                Bs[kk * 68 + col] = m2[(a0 + kk) * 512 + c0 + col];
            }
            __syncthreads();
#pragma unroll 8
            for (int kk = 0; kk < 32; ++kk) {
                float av0 = As[kk * 33 + 2 * ty], av1 = As[kk * 33 + 2 * ty + 1];
                float4 bv = *(float4*)&Bs[kk * 68 + 4 * tx];
                a00 += av0 * bv.x; a01 += av0 * bv.y; a02 += av0 * bv.z; a03 += av0 * bv.w;
                a10 += av1 * bv.x; a11 += av1 * bv.y; a12 += av1 * bv.z; a13 += av1 * bv.w;
            }
        }
        int b_ = b0 + 2 * ty;
        float rowv[2][4] = {{a00, a01, a02, a03}, {a10, a11, a12, a13}};
#pragma unroll
        for (int jj = 0; jj < 4; ++jj) {
            int col = c0 + 4 * tx + jj;
            int I = col >> 7, p = col & 127;
            Tn[I * 16384 + p * 128 + b_] = rowv[0][jj];
            Tn[I * 16384 + p * 128 + b_ + 1] = rowv[1][jj];
        }
    }
}

// ---------------- phase B (512 threads) -------------------------------------
// Energy blocks 0..127: tile 32 rows x 64 cols, 4x8 microtile, 8-way wave-
// aligned k-split (z = t>>6, 64 k each), LDS reduce + distributed store.
// Norm blocks 128..143: R11 verbatim (z = t>>8 two-way k-split).
__global__ __launch_bounds__(512) void k_B2(float* __restrict__ ws, int k) {
    __shared__ __align__(16) float sm[26624];
    int bid = blockIdx.x, t = threadIdx.x;
    if (bid < 128) {
        int side = bid >> 6;
        int eb = bid & 63;
        int r0 = (eb & 31) * 32;
        int c0 = (eb >> 5) * 64;
        const float* A = ws + (side ? OFF_T2R : OFF_T2L);
        const float* B = ws + (side ? OFF_MR2 : OFF_M2) + k * M2SZ;
        float* C = ws + (side ? OFF_LR : OFF_LL);
        int z = t >> 6, tl = t & 63;        // z = wave id (8), 64 thr each
        int ty = tl >> 3, tx = tl & 7;      // 8x8 positions; microtile 4x8
        float acc[4][8];
#pragma unroll
        for (int j = 0; j < 4; ++j)
#pragma unroll
            for (int q = 0; q < 8; ++q) acc[j][q] = 0.f;
        float* As = sm + z * 3328;          // [32k][36] (4-row b128 aligned)
        float* Bs = sm + z * 3328 + 1152;   // [32k][68]
        int arr[4], akq[4], bkk[8], bcq[8];
#pragma unroll
        for (int u = 0; u < 4; ++u) {
            int e = u * 64 + tl;
            arr[u] = e >> 3; akq[u] = e & 7;
        }
#pragma unroll
        for (int u = 0; u < 8; ++u) {
            int e = u * 64 + tl;
            bkk[u] = e >> 4; bcq[u] = e & 15;
        }
        float4 pa[4], pb[8];
        {
            int k0 = z * 64;
#pragma unroll
            for (int u = 0; u < 4; ++u)
                pa[u] = *(const float4*)&A[(r0 + arr[u]) * 512 + k0 + akq[u] * 4];
#pragma unroll
            for (int u = 0; u < 8; ++u) {
                int row = k0 + bkk[u];
                pb[u] = *(const float4*)&B[(row >> 2) * 512 + (row & 3) * 128 + c0 + bcq[u] * 4];
            }
        }
        for (int c = 0; c < 2; ++c) {
            __syncthreads();
#pragma unroll
            for (int u = 0; u < 4; ++u) {   // transpose-scatter A into As[kk][36]
                float* dst = &As[(akq[u] * 4) * 36 + arr[u]];
                dst[0] = pa[u].x; dst[36] = pa[u].y; dst[72] = pa[u].z; dst[108] = pa[u].w;
            }
#pragma unroll
            for (int u = 0; u < 8; ++u)
                *(float4*)&Bs[bkk[u] * 68 + bcq[u] * 4] = pb[u];
            if (c == 0) {
                int k0 = z * 64 + 32;
#pragma unroll
                for (int u = 0; u < 4; ++u)
                    pa[u] = *(const float4*)&A[(r0 + arr[u]) * 512 + k0 + akq[u] * 4];
#pragma unroll
                for (int u = 0; u < 8; ++u) {
                    int row = k0 + bkk[u];
                    pb[u] = *(const float4*)&B[(row >> 2) * 512 + (row & 3) * 128 + c0 + bcq[u] * 4];
                }
            }
            __syncthreads();
#pragma unroll 8
            for (int kk = 0; kk < 32; ++kk) {
                float4 av = *(float4*)&As[kk * 36 + ty * 4];
                float4 bv0 = *(float4*)&Bs[kk * 68 + tx * 8];
                float4 bv1 = *(float4*)&Bs[kk * 68 + tx * 8 + 4];
                float avv[4] = {av.x, av.y, av.z, av.w};
#pragma unroll
                for (int j = 0; j < 4; ++j) {
                    acc[j][0] += avv[j] * bv0.x; acc[j][1] += avv[j] * bv0.y;
                    acc[j][2] += avv[j] * bv0.z; acc[j][3] += avv[j] * bv0.w;
                    acc[j][4] += avv[j] * bv1.x; acc[j][5] += avv[j] * bv1.y;
                    acc[j][6] += avv[j] * bv1.z; acc[j][7] += avv[j] * bv1.w;
                }
            }
        }
        // 8-way reduce: red[z][pos64][32] aliases As/Bs (dead after sync)
        __syncthreads();
        float* red = sm;
#pragma unroll
        for (int j = 0; j < 4; ++j) {
#pragma unroll
            for (int qq = 0; qq < 2; ++qq) {
                float4 v;
                v.x = acc[j][qq * 4]; v.y = acc[j][qq * 4 + 1];
                v.z = acc[j][qq * 4 + 2]; v.w = acc[j][qq * 4 + 3];
                *(float4*)&red[z * 2048 + tl * 32 + j * 8 + qq * 4] = v;
            }
        }
        __syncthreads();
        {   // thread t sums 4 consecutive vals of one position across 8 z
            int pos = t >> 3;
            int vi0 = (t & 7) * 4;
            float4 s;
            s.x = 0.f; s.y = 0.f; s.z = 0.f; s.w = 0.f;
#pragma unroll
            for (int zz = 0; zz < 8; ++zz) {
                float4 v = *(float4*)&red[zz * 2048 + pos * 32 + vi0];
                s.x += v.x; s.y += v.y; s.z += v.z; s.w += v.w;
            }
            int j = vi0 >> 3;                 // row-sub (vi0 in {0,4,..,28}, j const)
            int q0 = vi0 & 7;                 // 0 or 4
            int r = r0 + (pos >> 3) * 4 + j;
            int cc = c0 + (pos & 7) * 8 + q0;
            *(float4*)&C[(r >> 3) * 1024 + (r & 7) * 128 + cc] = s;
        }
    } else if (bid < 144) {
        int z = t >> 8, tl = t & 255;       // R11 norm path verbatim
        int ty = tl >> 4, tx = tl & 15;
        float a00 = 0, a01 = 0, a02 = 0, a03 = 0;
        float a10 = 0, a11 = 0, a12 = 0, a13 = 0;
        float* As = sm + z * 3264;
        float* Bs = sm + z * 3264 + 1088;
        float* red = sm + 6528;
        int g = bid - 128;
        int side = g >> 3;
        int nn = g & 7;
        int r0 = (nn & 3) * 32;
        int c0 = (nn >> 2) * 64;
        const float* A = ws + (side ? OFF_TNR : OFF_TNL);
        const float* B = ws + (side ? OFF_MR2 : OFF_M2) + k * M2SZ;
        float* C = ws + (side ? OFF_NR : OFF_NL);
        for (int c = 0; c < 8; ++c) {
            int cg = z * 8 + c;
            int Ic = cg >> 2, bc = (cg & 3) * 32;
            __syncthreads();
            {
                int rr = tl >> 3, kq = tl & 7;
                const float4 v = *(const float4*)&A[Ic * 16384 + (r0 + rr) * 128 + bc + kq * 4];
                float* dst = &As[kq * 136 + rr];
                dst[0] = v.x; dst[34] = v.y; dst[68] = v.z; dst[102] = v.w;
            }
#pragma unroll
            for (int u = 0; u < 2; ++u) {
                int e = u * 256 + tl;
                int kk = e >> 4, cq = e & 15;
                const float4 v = *(const float4*)&B[(bc + kk) * 512 + Ic * 128 + c0 + cq * 4];
                *(float4*)&Bs[kk * 68 + cq * 4] = v;
            }
            __syncthreads();
#pragma unroll 8
            for (int kk = 0; kk < 32; ++kk) {
                float av0 = As[kk * 34 + 2 * ty], av1 = As[kk * 34 + 2 * ty + 1];
                float4 bv = *(float4*)&Bs[kk * 68 + 4 * tx];
                a00 += av0 * bv.x; a01 += av0 * bv.y; a02 += av0 * bv.z; a03 += av0 * bv.w;
                a10 += av1 * bv.x; a11 += av1 * bv.y; a12 += av1 * bv.z; a13 += av1 * bv.w;
            }
        }
        __syncthreads();
        if (z == 1) {
            float4 v0; v0.x = a00; v0.y = a01; v0.z = a02; v0.w = a03;
            float4 v1; v1.x = a10; v1.y = a11; v1.z = a12; v1.w = a13;
            *(float4*)&red[tl * 8] = v0;
            *(float4*)&red[tl * 8 + 4] = v1;
        }
        __syncthreads();
        if (z == 0) {
            float4 v0 = *(float4*)&red[tl * 8];
            float4 v1 = *(float4*)&red[tl * 8 + 4];
            a00 += v0.x; a01 += v0.y; a02 += v0.z; a03 += v0.w;
            a10 += v1.x; a11 += v1.y; a12 += v1.z; a13 += v1.w;
            int r = r0 + 2 * ty, cc = c0 + 4 * tx;
            float4 w0; w0.x = a00; w0.y = a01; w0.z = a02; w0.w = a03;
            float4 w1; w1.x = a10; w1.y = a11; w1.z = a12; w1.w = a13;
            *(float4*)&C[r * 128 + cc] = w0;
            *(float4*)&C[(r + 1) * 128 + cc] = w1;
        }
    }
}

// ---------------- dot partials + loss (R11 verbatim) ------------------------
__global__ __launch_bounds__(256) void k_dot(float* __restrict__ ws) {
    __shared__ float se[256], sn[256];
    int bid = blockIdx.x, t = threadIdx.x;
    const float* LL = ws + OFF_LL;
    const float* LR = ws + OFF_LR;
    float e = 0.f;
#pragma unroll
    for (int u = 0; u < 4; ++u) {
        int i = bid * 1024 + u * 256 + t;
        e += LL[i] * LR[i];
    }
    float n = 0.f;
    if (t < 128) {
        int i = bid * 128 + t;
        n = ws[OFF_NL + i] * ws[OFF_NR + i];
    }
    se[t] = e;
    sn[t] = n;
    __syncthreads();
    for (int s = 128; s > 0; s >>= 1) {
        if (t < s) { se[t] += se[t + s]; sn[t] += sn[t + s]; }
        __syncthreads();
    }
    if (t == 0) {
        ws[OFF_PART + bid] = se[0];
        ws[OFF_PARTN + bid] = sn[0];
    }
}

__global__ __launch_bounds__(256) void k_loss(const float* __restrict__ ws,
                                              float* __restrict__ out) {
    __shared__ float se[128], sn[128];
    int t = threadIdx.x;
    if (t < 128) {
        se[t] = ws[OFF_PART + t];
        sn[t] = ws[OFF_PARTN + t];
    }
    __syncthreads();
    for (int s = 64; s > 0; s >>= 1) {
        if (t < s) { se[t] += se[t + s]; sn[t] += sn[t + s]; }
        __syncthreads();
    }
    if (t == 0) {
        float E = se[0], Nm = sn[0];
        out[0] = E;
        out[1] = Nm;
        out[2] = E / Nm;
        out[3] = fmaxf(Nm - 10000.0f, 0.0f);
    }
}

extern "C" void kernel_launch(void* const* d_in, const int* in_sizes, int n_in,
                              void* d_out, int out_size, void* d_ws, size_t ws_size,
                              hipStream_t stream) {
    const float* Min = (const float*)d_in[0];
    const float* Hin = (const float*)d_in[1];
    float* ws = (float*)d_ws;
    float* out = (float*)d_out;
    (void)in_sizes; (void)n_in; (void)out_size; (void)ws_size;

    k_prep1<<<dim3(641), dim3(256), 0, stream>>>(Min, Hin, ws);
    k_prep2<<<dim3(640), dim3(256), 0, stream>>>(ws);
    for (int k = 0; k < HALF2; ++k) {
        k_A2<<<dim3(160), dim3(512), 0, stream>>>(ws, k);
        k_B2<<<dim3(144), dim3(512), 0, stream>>>(ws, k);
    }
    k_dot<<<dim3(128), dim3(256), 0, stream>>>(ws);
    k_loss<<<dim3(1), dim3(256), 0, stream>>>(ws, out);
}